// Round 2
// 836.474 us; speedup vs baseline: 1.3884x; 1.3884x over previous
//
#include <hip/hip_runtime.h>
#include <stdint.h>

#define B_  32
#define T_  64
#define V_  32000
#define E_  256
#define H_  512
#define TS  63

typedef __attribute__((ext_vector_type(8))) short short8;
typedef __attribute__((ext_vector_type(4))) float floatx4;

union U16c { uint4 u; short8 s; };

__device__ __forceinline__ short8 ld8(const unsigned short* p) {
    U16c x; x.u = *(const uint4*)p; return x.s;
}

__device__ __forceinline__ unsigned short f2bf(float f) {
    union { float f; unsigned u; } v; v.f = f;
    unsigned r = v.u + 0x7FFFu + ((v.u >> 16) & 1u);
    return (unsigned short)(r >> 16);
}

// ---------------- setup: convert W_proj to bf16 ----------------
__global__ void k_cvt_wp(const float* __restrict__ wp, unsigned short* __restrict__ dst) {
    int i = blockIdx.x * blockDim.x + threadIdx.x;   // 2,048,000 threads, 8 elems each
    const float4* s = (const float4*)wp + (size_t)i * 2;
    float4 a = s[0], b = s[1];
    union { uint4 u; unsigned short h[8]; } o;
    o.h[0] = f2bf(a.x); o.h[1] = f2bf(a.y); o.h[2] = f2bf(a.z); o.h[3] = f2bf(a.w);
    o.h[4] = f2bf(b.x); o.h[5] = f2bf(b.y); o.h[6] = f2bf(b.z); o.h[7] = f2bf(b.w);
    ((uint4*)dst)[i] = o.u;
}

// ---------------- setup: W_ih/W_hh bf16, emb gather (+pad), h0 row, flag zero ----------------
__global__ void k_setup(const float* __restrict__ wih, const float* __restrict__ whh,
                        const float* __restrict__ embt, const int* __restrict__ trg,
                        const float* __restrict__ h0,
                        unsigned short* __restrict__ wih_bf, unsigned short* __restrict__ whh_bf,
                        unsigned short* __restrict__ emb_bf, unsigned short* __restrict__ hall,
                        unsigned* __restrict__ flags)
{
    const int NIH  = (3 * H_ * E_) / 4;   // 98304
    const int NHH  = (3 * H_ * H_) / 4;   // 196608
    const int NEMB = TS * B_ * E_ / 4;    // 129024
    const int NPAD = 32 * E_ / 8;         // 1024 uint4: zero emb rows 2016..2047 (k_xg M pad)
    const int NH0  = B_ * H_ / 4;         // 4096
    const int NFLG = TS * 32 * 32 * 4 / 16; // 16128 uint4: zero 252 KB flag region
    int i = blockIdx.x * blockDim.x + threadIdx.x;
    if (i < NIH + NHH) {
        const float* src; unsigned short* dst; int j;
        if (i < NIH) { src = wih; dst = wih_bf; j = i; }
        else         { src = whh; dst = whh_bf; j = i - NIH; }
        float4 v = ((const float4*)src)[j];
        union { unsigned long long u; unsigned short h[4]; } o;
        o.h[0] = f2bf(v.x); o.h[1] = f2bf(v.y); o.h[2] = f2bf(v.z); o.h[3] = f2bf(v.w);
        ((unsigned long long*)dst)[j] = o.u;
        return;
    }
    i -= NIH + NHH;
    if (i < NEMB) {
        int r = i >> 6, c = i & 63;          // r = t*32+b, 64 float4 per 256-wide row
        int tt = r >> 5, b = r & 31;
        int tok = trg[b * T_ + tt];
        float4 v = ((const float4*)(embt + (size_t)tok * E_))[c];
        union { unsigned long long u; unsigned short h[4]; } o;
        o.h[0] = f2bf(v.x); o.h[1] = f2bf(v.y); o.h[2] = f2bf(v.z); o.h[3] = f2bf(v.w);
        ((unsigned long long*)(emb_bf + (size_t)r * E_))[c] = o.u;
        return;
    }
    i -= NEMB;
    if (i < NPAD) {                           // zero-fill emb pad rows (feed only unread gx rows)
        uint4 z; z.x = z.y = z.z = z.w = 0u;
        ((uint4*)(emb_bf + (size_t)(TS * B_) * E_))[i] = z;
        return;
    }
    i -= NPAD;
    if (i < NH0) {
        float4 v = ((const float4*)h0)[i];
        union { unsigned long long u; unsigned short h[4]; } o;
        o.h[0] = f2bf(v.x); o.h[1] = f2bf(v.y); o.h[2] = f2bf(v.z); o.h[3] = f2bf(v.w);
        ((unsigned long long*)hall)[i] = o.u;   // Hall step-0 rows == h0
        return;
    }
    i -= NH0;
    if (i < NFLG) {                           // zero per-step/per-block ready flags
        uint4 z; z.x = z.y = z.z = z.w = 0u;
        ((uint4*)flags)[i] = z;
        return;
    }
}

// ---------------- x-gates GEMM: gx = emb_bf @ W_ih^T + b_ih ----------------
// M=2048 (63*32 live rows + 32 pad), N=1536, K=256. Hoisted out of the recurrence:
// x_gates are h-independent, so the serial k_gru loop shouldn't recompute them.
// Same 16x16x32 MFMA + same k-order as before => bit-identical gx values.
// NOTE: out points into d_out scratch (262 MB) — NOT workspace. k_gemm
// overwrites this region only after k_gru has finished reading it
// (stream-ordered), so no extra workspace is consumed.
__global__ __launch_bounds__(256) void k_xg(const unsigned short* __restrict__ A,
                                            const unsigned short* __restrict__ Bm,
                                            const float* __restrict__ bias,
                                            float* __restrict__ out)
{
    __shared__ unsigned short As[128 * 32];
    __shared__ unsigned short Bs[128 * 32];
    int m0 = blockIdx.x * 128, n0 = blockIdx.y * 128;
    int tid = threadIdx.x;
    int lane = tid & 63, w = tid >> 6;
    int wm = (w & 1) * 64, wn = (w >> 1) * 64;
    int row = lane & 15, quad = lane >> 4;
    int srow = lane >> 2, skc = lane & 3;
    floatx4 acc[4][4];
    #pragma unroll
    for (int a = 0; a < 4; ++a)
        #pragma unroll
        for (int b = 0; b < 4; ++b) acc[a][b] = (floatx4){0.f, 0.f, 0.f, 0.f};

    for (int k0 = 0; k0 < E_; k0 += 32) {
        if (k0) __syncthreads();
        #pragma unroll
        for (int p = 0; p < 2; ++p) {
            int seg = w * 2 + p;
            int m = seg * 16 + srow;
            __builtin_amdgcn_global_load_lds(
                (const __attribute__((address_space(1))) void*)(A + (size_t)(m0 + m) * E_ + k0 + skc * 8),
                (__attribute__((address_space(3))) void*)(As + seg * 512),
                16, 0, 0);
            __builtin_amdgcn_global_load_lds(
                (const __attribute__((address_space(1))) void*)(Bm + (size_t)(n0 + m) * E_ + k0 + skc * 8),
                (__attribute__((address_space(3))) void*)(Bs + seg * 512),
                16, 0, 0);
        }
        __syncthreads();
        short8 af[4], bf[4];
        #pragma unroll
        for (int mi2 = 0; mi2 < 4; ++mi2)
            af[mi2] = ld8(As + (wm + mi2 * 16 + row) * 32 + quad * 8);
        #pragma unroll
        for (int ni = 0; ni < 4; ++ni)
            bf[ni] = ld8(Bs + (wn + ni * 16 + row) * 32 + quad * 8);
        #pragma unroll
        for (int mi2 = 0; mi2 < 4; ++mi2)
            #pragma unroll
            for (int ni = 0; ni < 4; ++ni)
                acc[mi2][ni] = __builtin_amdgcn_mfma_f32_16x16x32_bf16(af[mi2], bf[ni], acc[mi2][ni], 0, 0, 0);
    }
    #pragma unroll
    for (int ni = 0; ni < 4; ++ni) {
        int n = n0 + wn + ni * 16 + row;
        float bp = bias[n];
        #pragma unroll
        for (int mi2 = 0; mi2 < 4; ++mi2) {
            #pragma unroll
            for (int v = 0; v < 4; ++v) {
                int m = m0 + wm + mi2 * 16 + quad * 4 + v;
                out[(size_t)m * 1536 + n] = acc[mi2][ni][v] + bp;
            }
        }
    }
}

// ---------------- GRU recurrence: 32 blocks x 512 threads ----------------
// Block i owns h-dims [i*16, i*16+16) for ALL 32 batch rows.
//  1. W_hh fragments live in REGISTERS (16x short8 = 64 VGPR per MFMA wave),
//     loaded once in the prologue — no per-step weight traffic.
//  2. x-gates precomputed by k_xg — per step only 3 fp32 loads, prefetched
//     before the flag wait.
//  3. Sync: contended cnt[t] fetch_add (32 cross-XCD RMWs to ONE word,
//     serialized at L3) replaced by per-block ready flags padded to 128 B.
//     Producers: relaxed store after __syncthreads drains vmcnt (all
//     write-through h stores acked at L3). Consumers: wave 0 polls all 32
//     flags in parallel (one load across 32 cachelines + __any). No RMW.
//     hall is t-indexed and drift is bounded to 1 step by the wait itself,
//     so producer-done flags suffice (no full symmetric barrier needed).
__global__ __launch_bounds__(512) void k_gru(
    const unsigned short* __restrict__ whh_bf, const float* __restrict__ gx,
    const float* __restrict__ bhh, const float* __restrict__ h0,
    unsigned short* __restrict__ hall, unsigned* __restrict__ flags)
{
    __shared__ unsigned short hs[32 * 528];  // 33.8 KB, stride 528 (16B-aligned rows, conflict-free b128)
    __shared__ float gh[32][52];
    unsigned* hallw = (unsigned*)hall;
    int blk = blockIdx.x, tid = threadIdx.x;
    int lane = tid & 63, w = tid >> 6;
    int mi = w & 1, gi = w >> 1;
    int row = lane & 15, quad = lane >> 4;
    int eb = tid >> 4, jl = tid & 15;       // elementwise: batch, local j
    int j = blk * 16 + jl;

    float bhhr = bhh[j], bhhz = bhh[H_ + j], bhhn = bhh[2*H_ + j];
    float hcur = h0[eb * H_ + j];           // fp32 h state lives in a register

    // prologue: W_hh fragments -> registers (waves 0..5), resident for all 63 steps
    short8 barr[16];
    if (w < 6) {
        int gr = gi * H_ + blk * 16 + row;
        const unsigned short* wrow = whh_bf + (size_t)gr * H_;
        #pragma unroll
        for (int kk = 0; kk < 16; ++kk)
            barr[kk] = ld8(wrow + kk * 32 + quad * 8);
    }

    for (int t = 0; t < TS; ++t) {
        // prefetch x-gates (h-independent): latency overlaps the flag wait
        const float* gxp = gx + (size_t)(t * B_ + eb) * 1536 + j;
        float xr = gxp[0], xz = gxp[512], xn = gxp[1024];

        if (t > 0) {
            if (w == 0) {
                const unsigned* f = flags + ((size_t)(t - 1) * 32 + (lane & 31)) * 32;
                unsigned v;
                do { v = __hip_atomic_load(f, __ATOMIC_RELAXED, __HIP_MEMORY_SCOPE_AGENT); }
                while (__any(v == 0));
            }
            __syncthreads();
        }

        // ---- stage hall[t] (32x512 bf16 = 32 KB) into LDS, coherent dword loads ----
        #pragma unroll
        for (int i = 0; i < 16; ++i) {
            int idx = tid + i * 512;
            int r = idx >> 8, c = idx & 255;     // 256 dwords per 512-bf16 row
            unsigned v = __hip_atomic_load(hallw + ((size_t)t * B_ + r) * (H_ / 2) + c,
                                           __ATOMIC_RELAXED, __HIP_MEMORY_SCOPE_AGENT);
            ((unsigned*)(hs + (size_t)r * 528))[c] = v;
        }
        __syncthreads();

        if (w < 6) {
            floatx4 ah = {0.f, 0.f, 0.f, 0.f};
            int b_ = mi * 16 + row;                      // A-operand m = batch
            #pragma unroll
            for (int kk = 0; kk < 16; ++kk)
                ah = __builtin_amdgcn_mfma_f32_16x16x32_bf16(
                        ld8(hs + b_ * 528 + kk * 32 + quad * 8), barr[kk], ah, 0, 0, 0);
            // C/D layout: col(n)=lane&15, row(m)=quad*4+v
            int cb = mi * 16 + quad * 4;
            int cn = gi * 16 + row;
            #pragma unroll
            for (int v = 0; v < 4; ++v) gh[cb + v][cn] = ah[v];
        }
        __syncthreads();
        {
            float hr = gh[eb][jl], hz = gh[eb][16 + jl], hn = gh[eb][32 + jl];
            float r = 1.f / (1.f + __expf(-(xr + hr + bhhr)));
            float z = 1.f / (1.f + __expf(-(xz + hz + bhhz)));
            float nn = tanhf(xn + r * (hn + bhhn));
            hcur = (1.f - z) * nn + z * hcur;
            // pack pair (j even, j odd) into one dword; write-through to L3
            float hnb = __shfl_xor(hcur, 1);
            if (!(tid & 1)) {
                unsigned pk = (unsigned)f2bf(hcur) | ((unsigned)f2bf(hnb) << 16);
                __hip_atomic_store(hallw + ((size_t)(t + 1) * B_ + eb) * (H_ / 2) + (j >> 1),
                                   pk, __ATOMIC_RELAXED, __HIP_MEMORY_SCOPE_AGENT);
            }
        }
        __syncthreads();   // drains vmcnt: all coherent h stores acked at L3 before flag
        if (t < TS - 1 && tid == 0)
            __hip_atomic_store(flags + ((size_t)t * 32 + blk) * 32, 1u,
                               __ATOMIC_RELAXED, __HIP_MEMORY_SCOPE_AGENT);
    }
}

// ---------------- projection GEMM: logits = Hall @ Wp^T + b_proj ----------------
// M=2048 (64 steps x 32 batch), N=32000, K=512. 128x128 tile, 4 waves x 64x64.
// m97-style staging: global_load_lds width=16, lane-contiguous unpadded [m][32] LDS.
__global__ __launch_bounds__(256) void k_gemm(const unsigned short* __restrict__ A,
                                              const unsigned short* __restrict__ Bm,
                                              const float* __restrict__ bias,
                                              float* __restrict__ out)
{
    __shared__ unsigned short As[128 * 32];   // 8 KB, row stride 32 shorts (64 B) — no pad
    __shared__ unsigned short Bs[128 * 32];
    int m0 = blockIdx.x * 128, n0 = blockIdx.y * 128;
    int tid = threadIdx.x;
    int lane = tid & 63, w = tid >> 6;
    int wm = (w & 1) * 64, wn = (w >> 1) * 64;
    int row = lane & 15, quad = lane >> 4;
    int srow = lane >> 2, skc = lane & 3;     // staging: lane -> (row-in-16, k-chunk)
    floatx4 acc[4][4];
    #pragma unroll
    for (int a = 0; a < 4; ++a)
        #pragma unroll
        for (int b = 0; b < 4; ++b) acc[a][b] = (floatx4){0.f, 0.f, 0.f, 0.f};

    for (int k0 = 0; k0 < H_; k0 += 32) {
        if (k0) __syncthreads();
        #pragma unroll
        for (int p = 0; p < 2; ++p) {
            int seg = w * 2 + p;              // 0..7, 16 rows each
            int m = seg * 16 + srow;
            __builtin_amdgcn_global_load_lds(
                (const __attribute__((address_space(1))) void*)(A + (size_t)(m0 + m) * H_ + k0 + skc * 8),
                (__attribute__((address_space(3))) void*)(As + seg * 512),
                16, 0, 0);
            __builtin_amdgcn_global_load_lds(
                (const __attribute__((address_space(1))) void*)(Bm + (size_t)(n0 + m) * H_ + k0 + skc * 8),
                (__attribute__((address_space(3))) void*)(Bs + seg * 512),
                16, 0, 0);
        }
        __syncthreads();
        short8 af[4], bf[4];
        #pragma unroll
        for (int mi2 = 0; mi2 < 4; ++mi2)
            af[mi2] = ld8(As + (wm + mi2 * 16 + row) * 32 + quad * 8);
        #pragma unroll
        for (int ni = 0; ni < 4; ++ni)
            bf[ni] = ld8(Bs + (wn + ni * 16 + row) * 32 + quad * 8);
        #pragma unroll
        for (int mi2 = 0; mi2 < 4; ++mi2)
            #pragma unroll
            for (int ni = 0; ni < 4; ++ni)
                acc[mi2][ni] = __builtin_amdgcn_mfma_f32_16x16x32_bf16(af[mi2], bf[ni], acc[mi2][ni], 0, 0, 0);
    }
    // epilogue: remap Hall row m = step*32+b -> out row b*64+step; add bias
    #pragma unroll
    for (int ni = 0; ni < 4; ++ni) {
        int n = n0 + wn + ni * 16 + row;
        float bp = bias[n];
        #pragma unroll
        for (int mi2 = 0; mi2 < 4; ++mi2) {
            #pragma unroll
            for (int v = 0; v < 4; ++v) {
                int m = m0 + wm + mi2 * 16 + quad * 4 + v;
                int orow = (m & 31) * 64 + (m >> 5);
                out[(size_t)orow * V_ + n] = acc[mi2][ni][v] + bp;
            }
        }
    }
}

// ---------------- in-place log_softmax, one block per output row ----------------
__global__ __launch_bounds__(320) void k_lsm(float* __restrict__ out)
{
    __shared__ float red[5];
    int rown = blockIdx.x;
    int t = rown & 63;
    float4* p = (float4*)(out + (size_t)rown * V_);
    int tid = threadIdx.x;
    if (t == 0) {   // out[:,0,:] = 0 (must rewrite every launch: d_out is re-poisoned)
        float4 z; z.x = z.y = z.z = z.w = 0.f;
        for (int i = tid; i < V_ / 4; i += 320) p[i] = z;
        return;
    }
    float4 v[25];
    #pragma unroll
    for (int jj = 0; jj < 25; ++jj) v[jj] = p[tid + jj * 320];
    float m = -3.4e38f;
    #pragma unroll
    for (int jj = 0; jj < 25; ++jj)
        m = fmaxf(m, fmaxf(fmaxf(v[jj].x, v[jj].y), fmaxf(v[jj].z, v[jj].w)));
    #pragma unroll
    for (int o = 32; o > 0; o >>= 1) m = fmaxf(m, __shfl_xor(m, o));
    if ((tid & 63) == 0) red[tid >> 6] = m;
    __syncthreads();
    m = fmaxf(fmaxf(fmaxf(red[0], red[1]), fmaxf(red[2], red[3])), red[4]);
    __syncthreads();
    float s = 0.f;
    #pragma unroll
    for (int jj = 0; jj < 25; ++jj)
        s += __expf(v[jj].x - m) + __expf(v[jj].y - m) + __expf(v[jj].z - m) + __expf(v[jj].w - m);
    #pragma unroll
    for (int o = 32; o > 0; o >>= 1) s += __shfl_xor(s, o);
    if ((tid & 63) == 0) red[tid >> 6] = s;
    __syncthreads();
    s = red[0] + red[1] + red[2] + red[3] + red[4];
    float lz = m + logf(s);
    #pragma unroll
    for (int jj = 0; jj < 25; ++jj) {
        float4 o4;
        o4.x = v[jj].x - lz; o4.y = v[jj].y - lz; o4.z = v[jj].z - lz; o4.w = v[jj].w - lz;
        p[tid + jj * 320] = o4;
    }
}

extern "C" void kernel_launch(void* const* d_in, const int* in_sizes, int n_in,
                              void* d_out, int out_size, void* d_ws, size_t ws_size,
                              hipStream_t stream) {
    const int*   trg   = (const int*)d_in[0];
    const float* h0    = (const float*)d_in[1];
    const float* embt  = (const float*)d_in[2];
    const float* wih   = (const float*)d_in[3];
    const float* whh   = (const float*)d_in[4];
    const float* bih   = (const float*)d_in[5];
    const float* bhh   = (const float*)d_in[6];
    const float* wproj = (const float*)d_in[7];
    const float* bproj = (const float*)d_in[8];
    float* out = (float*)d_out;

    char* ws = (char*)d_ws;
    size_t off = 0;
    unsigned short* wp_bf  = (unsigned short*)(ws + off); off += (size_t)V_ * H_ * 2;        // 32.77 MB
    unsigned short* wih_bf = (unsigned short*)(ws + off); off += (size_t)3 * H_ * E_ * 2;    // 0.79 MB
    unsigned short* whh_bf = (unsigned short*)(ws + off); off += (size_t)3 * H_ * H_ * 2;    // 1.57 MB
    unsigned short* emb_bf = (unsigned short*)(ws + off); off += (size_t)64 * B_ * E_ * 2;   // 1.05 MB (32 pad rows)
    unsigned short* hall   = (unsigned short*)(ws + off); off += (size_t)64 * B_ * H_ * 2;   // 2.10 MB
    unsigned*       flags  = (unsigned*)(ws + off);       off += (size_t)TS * 32 * 32 * 4;   // 0.26 MB
    // gx lives in d_out scratch (12.58 MB of 262 MB). Written by k_xg, read by
    // k_gru, then overwritten by k_gemm — all stream-ordered. Keeps workspace
    // at the proven ~38.5 MB footprint.
    float*          gx     = (float*)d_out;

    k_cvt_wp<<<8000, 256, 0, stream>>>(wproj, wp_bf);                       // V*H/8 threads exact
    k_setup<<<1739, 256, 0, stream>>>(wih, whh, embt, trg, h0,
                                      wih_bf, whh_bf, emb_bf, hall, flags);
    dim3 xg(16, 12);
    k_xg<<<xg, 256, 0, stream>>>(emb_bf, wih_bf, bih, gx);
    k_gru<<<32, 512, 0, stream>>>(whh_bf, gx, bhh, h0, hall, flags);
    dim3 gg(16, 250);
    k_gemm<<<gg, 256, 0, stream>>>(hall, wp_bf, bproj, out);
    k_lsm<<<2048, 320, 0, stream>>>(out);
}

// Round 3
// 687.406 us; speedup vs baseline: 1.6895x; 1.2169x over previous
//
#include <hip/hip_runtime.h>
#include <stdint.h>

#define B_  32
#define T_  64
#define V_  32000
#define E_  256
#define H_  512
#define TS  63

typedef __attribute__((ext_vector_type(8))) short short8;
typedef __attribute__((ext_vector_type(4))) float floatx4;

union U16c { uint4 u; short8 s; };

__device__ __forceinline__ short8 ld8(const unsigned short* p) {
    U16c x; x.u = *(const uint4*)p; return x.s;
}

__device__ __forceinline__ unsigned short f2bf(float f) {
    union { float f; unsigned u; } v; v.f = f;
    unsigned r = v.u + 0x7FFFu + ((v.u >> 16) & 1u);
    return (unsigned short)(r >> 16);
}

// ---------------- setup: convert W_proj to bf16 ----------------
__global__ void k_cvt_wp(const float* __restrict__ wp, unsigned short* __restrict__ dst) {
    int i = blockIdx.x * blockDim.x + threadIdx.x;   // 2,048,000 threads, 8 elems each
    const float4* s = (const float4*)wp + (size_t)i * 2;
    float4 a = s[0], b = s[1];
    union { uint4 u; unsigned short h[8]; } o;
    o.h[0] = f2bf(a.x); o.h[1] = f2bf(a.y); o.h[2] = f2bf(a.z); o.h[3] = f2bf(a.w);
    o.h[4] = f2bf(b.x); o.h[5] = f2bf(b.y); o.h[6] = f2bf(b.z); o.h[7] = f2bf(b.w);
    ((uint4*)dst)[i] = o.u;
}

// ---------------- setup: W_ih/W_hh bf16, emb gather (+pad), h0 rows, hall64 tags ----------------
__global__ void k_setup(const float* __restrict__ wih, const float* __restrict__ whh,
                        const float* __restrict__ embt, const int* __restrict__ trg,
                        const float* __restrict__ h0,
                        unsigned short* __restrict__ wih_bf, unsigned short* __restrict__ whh_bf,
                        unsigned short* __restrict__ emb_bf, unsigned short* __restrict__ hall,
                        unsigned long long* __restrict__ hall64)
{
    const int NIH  = (3 * H_ * E_) / 4;     // 98304
    const int NHH  = (3 * H_ * H_) / 4;     // 196608
    const int NEMB = TS * B_ * E_ / 4;      // 129024
    const int NPAD = 32 * E_ / 8;           // 1024 uint4: zero emb rows 2016..2047 (k_xg M pad)
    const int NH0  = B_ * H_ / 4;           // 4096
    const int NZ   = 63 * B_ * 256 * 8 / 16; // 258048 uint4: zero hall64[1..63] (tags MUST be
                                             // cleared every launch: stale tags from a previous
                                             // run would match this run's wanted tag values)
    int i = blockIdx.x * blockDim.x + threadIdx.x;
    if (i < NIH + NHH) {
        const float* src; unsigned short* dst; int j;
        if (i < NIH) { src = wih; dst = wih_bf; j = i; }
        else         { src = whh; dst = whh_bf; j = i - NIH; }
        float4 v = ((const float4*)src)[j];
        union { unsigned long long u; unsigned short h[4]; } o;
        o.h[0] = f2bf(v.x); o.h[1] = f2bf(v.y); o.h[2] = f2bf(v.z); o.h[3] = f2bf(v.w);
        ((unsigned long long*)dst)[j] = o.u;
        return;
    }
    i -= NIH + NHH;
    if (i < NEMB) {
        int r = i >> 6, c = i & 63;          // r = t*32+b, 64 float4 per 256-wide row
        int tt = r >> 5, b = r & 31;
        int tok = trg[b * T_ + tt];
        float4 v = ((const float4*)(embt + (size_t)tok * E_))[c];
        union { unsigned long long u; unsigned short h[4]; } o;
        o.h[0] = f2bf(v.x); o.h[1] = f2bf(v.y); o.h[2] = f2bf(v.z); o.h[3] = f2bf(v.w);
        ((unsigned long long*)(emb_bf + (size_t)r * E_))[c] = o.u;
        return;
    }
    i -= NEMB;
    if (i < NPAD) {                           // zero-fill emb pad rows (feed only unread gx rows)
        uint4 z; z.x = z.y = z.z = z.w = 0u;
        ((uint4*)(emb_bf + (size_t)(TS * B_) * E_))[i] = z;
        return;
    }
    i -= NPAD;
    if (i < NH0) {
        // h0 -> hall row 0 (plain bf16, for k_gemm) AND hall64 row 0 (tagged, tag=0, for k_gru)
        float4 v = ((const float4*)h0)[i];
        unsigned pk01 = (unsigned)f2bf(v.x) | ((unsigned)f2bf(v.y) << 16);
        unsigned pk23 = (unsigned)f2bf(v.z) | ((unsigned)f2bf(v.w) << 16);
        union { unsigned long long u; unsigned h[2]; } o;
        o.h[0] = pk01; o.h[1] = pk23;
        ((unsigned long long*)hall)[i] = o.u;
        uint4 tw; tw.x = pk01; tw.y = 0u; tw.z = pk23; tw.w = 0u;   // two u64 words, tag 0
        ((uint4*)hall64)[i] = tw;
        return;
    }
    i -= NH0;
    if (i < NZ) {
        uint4 z; z.x = z.y = z.z = z.w = 0u;
        ((uint4*)(hall64 + (size_t)B_ * 256))[i] = z;   // hall64[t=1..63] := 0 (tag 0 = invalid)
        return;
    }
}

// ---------------- x-gates GEMM: gx = emb_bf @ W_ih^T + b_ih ----------------
// M=2048 (63*32 live rows + 32 pad), N=1536, K=256. Same MFMA shape + K-order as the
// old in-loop computation => bit-identical gx. out points into d_out scratch.
__global__ __launch_bounds__(256) void k_xg(const unsigned short* __restrict__ A,
                                            const unsigned short* __restrict__ Bm,
                                            const float* __restrict__ bias,
                                            float* __restrict__ out)
{
    __shared__ unsigned short As[128 * 32];
    __shared__ unsigned short Bs[128 * 32];
    int m0 = blockIdx.x * 128, n0 = blockIdx.y * 128;
    int tid = threadIdx.x;
    int lane = tid & 63, w = tid >> 6;
    int wm = (w & 1) * 64, wn = (w >> 1) * 64;
    int row = lane & 15, quad = lane >> 4;
    int srow = lane >> 2, skc = lane & 3;
    floatx4 acc[4][4];
    #pragma unroll
    for (int a = 0; a < 4; ++a)
        #pragma unroll
        for (int b = 0; b < 4; ++b) acc[a][b] = (floatx4){0.f, 0.f, 0.f, 0.f};

    for (int k0 = 0; k0 < E_; k0 += 32) {
        if (k0) __syncthreads();
        #pragma unroll
        for (int p = 0; p < 2; ++p) {
            int seg = w * 2 + p;
            int m = seg * 16 + srow;
            __builtin_amdgcn_global_load_lds(
                (const __attribute__((address_space(1))) void*)(A + (size_t)(m0 + m) * E_ + k0 + skc * 8),
                (__attribute__((address_space(3))) void*)(As + seg * 512),
                16, 0, 0);
            __builtin_amdgcn_global_load_lds(
                (const __attribute__((address_space(1))) void*)(Bm + (size_t)(n0 + m) * E_ + k0 + skc * 8),
                (__attribute__((address_space(3))) void*)(Bs + seg * 512),
                16, 0, 0);
        }
        __syncthreads();
        short8 af[4], bf[4];
        #pragma unroll
        for (int mi2 = 0; mi2 < 4; ++mi2)
            af[mi2] = ld8(As + (wm + mi2 * 16 + row) * 32 + quad * 8);
        #pragma unroll
        for (int ni = 0; ni < 4; ++ni)
            bf[ni] = ld8(Bs + (wn + ni * 16 + row) * 32 + quad * 8);
        #pragma unroll
        for (int mi2 = 0; mi2 < 4; ++mi2)
            #pragma unroll
            for (int ni = 0; ni < 4; ++ni)
                acc[mi2][ni] = __builtin_amdgcn_mfma_f32_16x16x32_bf16(af[mi2], bf[ni], acc[mi2][ni], 0, 0, 0);
    }
    #pragma unroll
    for (int ni = 0; ni < 4; ++ni) {
        int n = n0 + wn + ni * 16 + row;
        float bp = bias[n];
        #pragma unroll
        for (int mi2 = 0; mi2 < 4; ++mi2) {
            #pragma unroll
            for (int v = 0; v < 4; ++v) {
                int m = m0 + wm + mi2 * 16 + quad * 4 + v;
                out[(size_t)m * 1536 + n] = acc[mi2][ni][v] + bp;
            }
        }
    }
}

// ---------------- GRU recurrence: 32 blocks x 512 threads ----------------
// Block i owns h-dims [i*16, i*16+16) for ALL 32 batch rows.
// v3: tagged-data sync — the data IS the flag. Each bf16 pair is stored as one
// 64-bit word [tag=t+1 | 2xbf16] with a single atomic store (8B = no tearing).
// Consumers load the words and retry until all tags match t: tag and payload
// arrive atomically together, so the flag round-trip, the vmcnt-drain barrier
// before it, and 2 of the 4 per-step __syncthreads all disappear. Serial
// cross-block chain per step = elementwise + store->L3 + retry-hit + MFMA
// (~3000-3500 cy). k_setup zeroes all tags each launch (stale tags from a
// previous run would otherwise match). Producers dual-store plain bf16 to
// hall for k_gemm (visible via kernel-boundary flush, same as h0 in r2).
__global__ __launch_bounds__(512) void k_gru(
    const unsigned short* __restrict__ whh_bf, const float* __restrict__ gx,
    const float* __restrict__ bhh, const float* __restrict__ h0,
    unsigned short* __restrict__ hall, unsigned long long* __restrict__ hall64)
{
    __shared__ unsigned short hs[32 * 528];  // 33.8 KB, stride 528 (16B-aligned rows, conflict-free b128)
    __shared__ float gh[32][52];
    int blk = blockIdx.x, tid = threadIdx.x;
    int lane = tid & 63, w = tid >> 6;
    int mi = w & 1, gi = w >> 1;
    int row = lane & 15, quad = lane >> 4;
    int eb = tid >> 4, jl = tid & 15;       // elementwise: batch, local j
    int j = blk * 16 + jl;

    float bhhr = bhh[j], bhhz = bhh[H_ + j], bhhn = bhh[2*H_ + j];
    float hcur = h0[eb * H_ + j];           // fp32 h state lives in a register

    // prologue: W_hh fragments -> registers (waves 0..5), resident for all 63 steps
    short8 barr[16];
    if (w < 6) {
        int gr = gi * H_ + blk * 16 + row;
        const unsigned short* wrow = whh_bf + (size_t)gr * H_;
        #pragma unroll
        for (int kk = 0; kk < 16; ++kk)
            barr[kk] = ld8(wrow + kk * 32 + quad * 8);
    }

    for (int t = 0; t < TS; ++t) {
        // prefetch x-gates (h-independent): latency overlaps the tag-poll
        const float* gxp = gx + (size_t)(t * B_ + eb) * 1536 + j;
        float xr = gxp[0], xz = gxp[512], xn = gxp[1024];

        // ---- tagged staging of hall64[t]: 8192 u64 words, 16 per thread ----
        const unsigned long long* src = hall64 + (size_t)t * (B_ * 256);
        unsigned long long wv[16];
        unsigned want = (unsigned)t;
        for (;;) {
            #pragma unroll
            for (int i = 0; i < 16; ++i)
                wv[i] = __hip_atomic_load(src + i * 512 + tid,
                                          __ATOMIC_RELAXED, __HIP_MEMORY_SCOPE_AGENT);
            bool ok = true;
            #pragma unroll
            for (int i = 0; i < 16; ++i) ok &= ((unsigned)(wv[i] >> 32) == want);
            if (ok) break;
        }
        #pragma unroll
        for (int i = 0; i < 16; ++i) {
            int idx = i * 512 + tid;                 // word idx: row=idx>>8, dword col=idx&255
            ((unsigned*)(hs + (size_t)(idx >> 8) * 528))[idx & 255] = (unsigned)wv[i];
        }
        __syncthreads();

        if (w < 6) {
            floatx4 ah = {0.f, 0.f, 0.f, 0.f};
            int b_ = mi * 16 + row;                      // A-operand m = batch
            #pragma unroll
            for (int kk = 0; kk < 16; ++kk)
                ah = __builtin_amdgcn_mfma_f32_16x16x32_bf16(
                        ld8(hs + b_ * 528 + kk * 32 + quad * 8), barr[kk], ah, 0, 0, 0);
            // C/D layout: col(n)=lane&15, row(m)=quad*4+v
            int cb = mi * 16 + quad * 4;
            int cn = gi * 16 + row;
            #pragma unroll
            for (int v = 0; v < 4; ++v) gh[cb + v][cn] = ah[v];
        }
        __syncthreads();
        {
            float hr = gh[eb][jl], hz = gh[eb][16 + jl], hn = gh[eb][32 + jl];
            float r = 1.f / (1.f + __expf(-(xr + hr + bhhr)));
            float z = 1.f / (1.f + __expf(-(xz + hz + bhhz)));
            float nn = tanhf(xn + r * (hn + bhhn));
            hcur = (1.f - z) * nn + z * hcur;
            // pack pair (j even, j odd); fire-and-forget: tagged word to hall64
            // (sync path) + plain bf16 to hall (k_gemm path). No drain, no flag.
            float hnb = __shfl_xor(hcur, 1);
            if (!(tid & 1)) {
                unsigned pk = (unsigned)f2bf(hcur) | ((unsigned)f2bf(hnb) << 16);
                unsigned long long tw = ((unsigned long long)(unsigned)(t + 1) << 32) | pk;
                __hip_atomic_store(hall64 + ((size_t)(t + 1) * B_ + eb) * 256 + (j >> 1),
                                   tw, __ATOMIC_RELAXED, __HIP_MEMORY_SCOPE_AGENT);
                ((unsigned*)hall)[((size_t)(t + 1) * B_ + eb) * 256 + (j >> 1)] = pk;
            }
        }
        // no end-of-step barrier: hs writes of step t+1 only occur after the
        // post-MFMA barrier above; gh reads complete before any thread reaches
        // the next stage barrier.
    }
}

// ---------------- projection GEMM: logits = Hall @ Wp^T + b_proj ----------------
// M=2048 (64 steps x 32 batch), N=32000, K=512. 128x128 tile, 4 waves x 64x64.
// m97-style staging: global_load_lds width=16, lane-contiguous unpadded [m][32] LDS.
__global__ __launch_bounds__(256) void k_gemm(const unsigned short* __restrict__ A,
                                              const unsigned short* __restrict__ Bm,
                                              const float* __restrict__ bias,
                                              float* __restrict__ out)
{
    __shared__ unsigned short As[128 * 32];   // 8 KB, row stride 32 shorts (64 B) — no pad
    __shared__ unsigned short Bs[128 * 32];
    int m0 = blockIdx.x * 128, n0 = blockIdx.y * 128;
    int tid = threadIdx.x;
    int lane = tid & 63, w = tid >> 6;
    int wm = (w & 1) * 64, wn = (w >> 1) * 64;
    int row = lane & 15, quad = lane >> 4;
    int srow = lane >> 2, skc = lane & 3;     // staging: lane -> (row-in-16, k-chunk)
    floatx4 acc[4][4];
    #pragma unroll
    for (int a = 0; a < 4; ++a)
        #pragma unroll
        for (int b = 0; b < 4; ++b) acc[a][b] = (floatx4){0.f, 0.f, 0.f, 0.f};

    for (int k0 = 0; k0 < H_; k0 += 32) {
        if (k0) __syncthreads();
        #pragma unroll
        for (int p = 0; p < 2; ++p) {
            int seg = w * 2 + p;              // 0..7, 16 rows each
            int m = seg * 16 + srow;
            __builtin_amdgcn_global_load_lds(
                (const __attribute__((address_space(1))) void*)(A + (size_t)(m0 + m) * H_ + k0 + skc * 8),
                (__attribute__((address_space(3))) void*)(As + seg * 512),
                16, 0, 0);
            __builtin_amdgcn_global_load_lds(
                (const __attribute__((address_space(1))) void*)(Bm + (size_t)(n0 + m) * H_ + k0 + skc * 8),
                (__attribute__((address_space(3))) void*)(Bs + seg * 512),
                16, 0, 0);
        }
        __syncthreads();
        short8 af[4], bf[4];
        #pragma unroll
        for (int mi2 = 0; mi2 < 4; ++mi2)
            af[mi2] = ld8(As + (wm + mi2 * 16 + row) * 32 + quad * 8);
        #pragma unroll
        for (int ni = 0; ni < 4; ++ni)
            bf[ni] = ld8(Bs + (wn + ni * 16 + row) * 32 + quad * 8);
        #pragma unroll
        for (int mi2 = 0; mi2 < 4; ++mi2)
            #pragma unroll
            for (int ni = 0; ni < 4; ++ni)
                acc[mi2][ni] = __builtin_amdgcn_mfma_f32_16x16x32_bf16(af[mi2], bf[ni], acc[mi2][ni], 0, 0, 0);
    }
    // epilogue: remap Hall row m = step*32+b -> out row b*64+step; add bias
    #pragma unroll
    for (int ni = 0; ni < 4; ++ni) {
        int n = n0 + wn + ni * 16 + row;
        float bp = bias[n];
        #pragma unroll
        for (int mi2 = 0; mi2 < 4; ++mi2) {
            #pragma unroll
            for (int v = 0; v < 4; ++v) {
                int m = m0 + wm + mi2 * 16 + quad * 4 + v;
                int orow = (m & 31) * 64 + (m >> 5);
                out[(size_t)orow * V_ + n] = acc[mi2][ni][v] + bp;
            }
        }
    }
}

// ---------------- in-place log_softmax, one block per output row ----------------
__global__ __launch_bounds__(320) void k_lsm(float* __restrict__ out)
{
    __shared__ float red[5];
    int rown = blockIdx.x;
    int t = rown & 63;
    float4* p = (float4*)(out + (size_t)rown * V_);
    int tid = threadIdx.x;
    if (t == 0) {   // out[:,0,:] = 0 (must rewrite every launch: d_out is re-poisoned)
        float4 z; z.x = z.y = z.z = z.w = 0.f;
        for (int i = tid; i < V_ / 4; i += 320) p[i] = z;
        return;
    }
    float4 v[25];
    #pragma unroll
    for (int jj = 0; jj < 25; ++jj) v[jj] = p[tid + jj * 320];
    float m = -3.4e38f;
    #pragma unroll
    for (int jj = 0; jj < 25; ++jj)
        m = fmaxf(m, fmaxf(fmaxf(v[jj].x, v[jj].y), fmaxf(v[jj].z, v[jj].w)));
    #pragma unroll
    for (int o = 32; o > 0; o >>= 1) m = fmaxf(m, __shfl_xor(m, o));
    if ((tid & 63) == 0) red[tid >> 6] = m;
    __syncthreads();
    m = fmaxf(fmaxf(fmaxf(red[0], red[1]), fmaxf(red[2], red[3])), red[4]);
    __syncthreads();
    float s = 0.f;
    #pragma unroll
    for (int jj = 0; jj < 25; ++jj)
        s += __expf(v[jj].x - m) + __expf(v[jj].y - m) + __expf(v[jj].z - m) + __expf(v[jj].w - m);
    #pragma unroll
    for (int o = 32; o > 0; o >>= 1) s += __shfl_xor(s, o);
    if ((tid & 63) == 0) red[tid >> 6] = s;
    __syncthreads();
    s = red[0] + red[1] + red[2] + red[3] + red[4];
    float lz = m + logf(s);
    #pragma unroll
    for (int jj = 0; jj < 25; ++jj) {
        float4 o4;
        o4.x = v[jj].x - lz; o4.y = v[jj].y - lz; o4.z = v[jj].z - lz; o4.w = v[jj].w - lz;
        p[tid + jj * 320] = o4;
    }
}

extern "C" void kernel_launch(void* const* d_in, const int* in_sizes, int n_in,
                              void* d_out, int out_size, void* d_ws, size_t ws_size,
                              hipStream_t stream) {
    const int*   trg   = (const int*)d_in[0];
    const float* h0    = (const float*)d_in[1];
    const float* embt  = (const float*)d_in[2];
    const float* wih   = (const float*)d_in[3];
    const float* whh   = (const float*)d_in[4];
    const float* bih   = (const float*)d_in[5];
    const float* bhh   = (const float*)d_in[6];
    const float* wproj = (const float*)d_in[7];
    const float* bproj = (const float*)d_in[8];
    float* out = (float*)d_out;

    char* ws = (char*)d_ws;
    size_t off = 0;
    unsigned short* wp_bf  = (unsigned short*)(ws + off); off += (size_t)V_ * H_ * 2;        // 32.77 MB
    unsigned short* wih_bf = (unsigned short*)(ws + off); off += (size_t)3 * H_ * E_ * 2;    // 0.79 MB
    unsigned short* whh_bf = (unsigned short*)(ws + off); off += (size_t)3 * H_ * H_ * 2;    // 1.57 MB
    unsigned short* emb_bf = (unsigned short*)(ws + off); off += (size_t)64 * B_ * E_ * 2;   // 1.05 MB (32 pad rows)
    unsigned short* hall   = (unsigned short*)(ws + off); off += (size_t)64 * B_ * H_ * 2;   // 2.10 MB
    // gx (12.58 MB) and hall64 (4.19 MB) live in d_out scratch (262 MB):
    // written by k_xg/k_setup/k_gru, consumed by k_gru, then overwritten by
    // k_gemm — all stream-ordered. Workspace stays at the proven 38.3 MB.
    float*              gx     = (float*)d_out;
    unsigned long long* hall64 = (unsigned long long*)((char*)d_out + (size_t)16 * 1024 * 1024);

    k_cvt_wp<<<8000, 256, 0, stream>>>(wproj, wp_bf);                       // V*H/8 threads exact
    k_setup<<<2684, 256, 0, stream>>>(wih, whh, embt, trg, h0,
                                      wih_bf, whh_bf, emb_bf, hall, hall64);
    dim3 xg(16, 12);
    k_xg<<<xg, 256, 0, stream>>>(emb_bf, wih_bf, bih, gx);
    k_gru<<<32, 512, 0, stream>>>(whh_bf, gx, bhh, h0, hall, hall64);
    dim3 gg(16, 250);
    k_gemm<<<gg, 256, 0, stream>>>(hall, wp_bf, bproj, out);
    k_lsm<<<2048, 320, 0, stream>>>(out);
}

// Round 4
// 653.371 us; speedup vs baseline: 1.7775x; 1.0521x over previous
//
#include <hip/hip_runtime.h>
#include <stdint.h>

#define B_  32
#define T_  64
#define V_  32000
#define E_  256
#define H_  512
#define TS  63

typedef __attribute__((ext_vector_type(8))) short short8;
typedef __attribute__((ext_vector_type(4))) float floatx4;

union U16c { uint4 u; short8 s; };

__device__ __forceinline__ short8 ld8(const unsigned short* p) {
    U16c x; x.u = *(const uint4*)p; return x.s;
}

__device__ __forceinline__ unsigned short f2bf(float f) {
    union { float f; unsigned u; } v; v.f = f;
    unsigned r = v.u + 0x7FFFu + ((v.u >> 16) & 1u);
    return (unsigned short)(r >> 16);
}

// ---------------- setup: convert W_proj to bf16 ----------------
__global__ void k_cvt_wp(const float* __restrict__ wp, unsigned short* __restrict__ dst) {
    int i = blockIdx.x * blockDim.x + threadIdx.x;   // 2,048,000 threads, 8 elems each
    const float4* s = (const float4*)wp + (size_t)i * 2;
    float4 a = s[0], b = s[1];
    union { uint4 u; unsigned short h[8]; } o;
    o.h[0] = f2bf(a.x); o.h[1] = f2bf(a.y); o.h[2] = f2bf(a.z); o.h[3] = f2bf(a.w);
    o.h[4] = f2bf(b.x); o.h[5] = f2bf(b.y); o.h[6] = f2bf(b.z); o.h[7] = f2bf(b.w);
    ((uint4*)dst)[i] = o.u;
}

// ---------------- setup: W_ih/W_hh bf16, emb gather (+pad), h0 row, hall64 tags ----------------
__global__ void k_setup(const float* __restrict__ wih, const float* __restrict__ whh,
                        const float* __restrict__ embt, const int* __restrict__ trg,
                        const float* __restrict__ h0,
                        unsigned short* __restrict__ wih_bf, unsigned short* __restrict__ whh_bf,
                        unsigned short* __restrict__ emb_bf,
                        unsigned long long* __restrict__ hall64)
{
    const int NIH  = (3 * H_ * E_) / 4;      // 98304
    const int NHH  = (3 * H_ * H_) / 4;      // 196608
    const int NEMB = TS * B_ * E_ / 4;       // 129024
    const int NPAD = 32 * E_ / 8;            // 1024 uint4: zero emb rows 2016..2047 (k_xg M pad)
    const int NH0  = B_ * H_ / 4;            // 4096
    const int NZ   = 63 * B_ * 256 * 8 / 16; // 258048 uint4: zero hall64[1..63] (tags MUST be
                                             // cleared every launch: stale tags from a previous
                                             // run would match this run's wanted tag values)
    int i = blockIdx.x * blockDim.x + threadIdx.x;
    if (i < NIH + NHH) {
        const float* src; unsigned short* dst; int j;
        if (i < NIH) { src = wih; dst = wih_bf; j = i; }
        else         { src = whh; dst = whh_bf; j = i - NIH; }
        float4 v = ((const float4*)src)[j];
        union { unsigned long long u; unsigned short h[4]; } o;
        o.h[0] = f2bf(v.x); o.h[1] = f2bf(v.y); o.h[2] = f2bf(v.z); o.h[3] = f2bf(v.w);
        ((unsigned long long*)dst)[j] = o.u;
        return;
    }
    i -= NIH + NHH;
    if (i < NEMB) {
        int r = i >> 6, c = i & 63;          // r = t*32+b, 64 float4 per 256-wide row
        int tt = r >> 5, b = r & 31;
        int tok = trg[b * T_ + tt];
        float4 v = ((const float4*)(embt + (size_t)tok * E_))[c];
        union { unsigned long long u; unsigned short h[4]; } o;
        o.h[0] = f2bf(v.x); o.h[1] = f2bf(v.y); o.h[2] = f2bf(v.z); o.h[3] = f2bf(v.w);
        ((unsigned long long*)(emb_bf + (size_t)r * E_))[c] = o.u;
        return;
    }
    i -= NEMB;
    if (i < NPAD) {                           // zero-fill emb pad rows (feed only unread gx rows)
        uint4 z; z.x = z.y = z.z = z.w = 0u;
        ((uint4*)(emb_bf + (size_t)(TS * B_) * E_))[i] = z;
        return;
    }
    i -= NPAD;
    if (i < NH0) {
        // h0 -> hall64 row 0 (tagged, tag=0). Tag convention: row R holds tag R>>5.
        float4 v = ((const float4*)h0)[i];
        unsigned pk01 = (unsigned)f2bf(v.x) | ((unsigned)f2bf(v.y) << 16);
        unsigned pk23 = (unsigned)f2bf(v.z) | ((unsigned)f2bf(v.w) << 16);
        uint4 tw; tw.x = pk01; tw.y = 0u; tw.z = pk23; tw.w = 0u;   // two u64 words, tag 0
        ((uint4*)hall64)[i] = tw;
        return;
    }
    i -= NH0;
    if (i < NZ) {
        uint4 z; z.x = z.y = z.z = z.w = 0u;
        ((uint4*)(hall64 + (size_t)B_ * 256))[i] = z;   // hall64[t=1..63] := 0 (tag 0 = invalid)
        return;
    }
}

// ---------------- x-gates GEMM: gx = emb_bf @ W_ih^T + b_ih ----------------
// M=2048 (63*32 live rows + 32 pad), N=1536, K=256. Same MFMA shape + K-order as the
// original in-loop computation => bit-identical gx values. gx lives in workspace.
__global__ __launch_bounds__(256) void k_xg(const unsigned short* __restrict__ A,
                                            const unsigned short* __restrict__ Bm,
                                            const float* __restrict__ bias,
                                            float* __restrict__ out)
{
    __shared__ unsigned short As[128 * 32];
    __shared__ unsigned short Bs[128 * 32];
    int m0 = blockIdx.x * 128, n0 = blockIdx.y * 128;
    int tid = threadIdx.x;
    int lane = tid & 63, w = tid >> 6;
    int wm = (w & 1) * 64, wn = (w >> 1) * 64;
    int row = lane & 15, quad = lane >> 4;
    int srow = lane >> 2, skc = lane & 3;
    floatx4 acc[4][4];
    #pragma unroll
    for (int a = 0; a < 4; ++a)
        #pragma unroll
        for (int b = 0; b < 4; ++b) acc[a][b] = (floatx4){0.f, 0.f, 0.f, 0.f};

    for (int k0 = 0; k0 < E_; k0 += 32) {
        if (k0) __syncthreads();
        #pragma unroll
        for (int p = 0; p < 2; ++p) {
            int seg = w * 2 + p;
            int m = seg * 16 + srow;
            __builtin_amdgcn_global_load_lds(
                (const __attribute__((address_space(1))) void*)(A + (size_t)(m0 + m) * E_ + k0 + skc * 8),
                (__attribute__((address_space(3))) void*)(As + seg * 512),
                16, 0, 0);
            __builtin_amdgcn_global_load_lds(
                (const __attribute__((address_space(1))) void*)(Bm + (size_t)(n0 + m) * E_ + k0 + skc * 8),
                (__attribute__((address_space(3))) void*)(Bs + seg * 512),
                16, 0, 0);
        }
        __syncthreads();
        short8 af[4], bf[4];
        #pragma unroll
        for (int mi2 = 0; mi2 < 4; ++mi2)
            af[mi2] = ld8(As + (wm + mi2 * 16 + row) * 32 + quad * 8);
        #pragma unroll
        for (int ni = 0; ni < 4; ++ni)
            bf[ni] = ld8(Bs + (wn + ni * 16 + row) * 32 + quad * 8);
        #pragma unroll
        for (int mi2 = 0; mi2 < 4; ++mi2)
            #pragma unroll
            for (int ni = 0; ni < 4; ++ni)
                acc[mi2][ni] = __builtin_amdgcn_mfma_f32_16x16x32_bf16(af[mi2], bf[ni], acc[mi2][ni], 0, 0, 0);
    }
    #pragma unroll
    for (int ni = 0; ni < 4; ++ni) {
        int n = n0 + wn + ni * 16 + row;
        float bp = bias[n];
        #pragma unroll
        for (int mi2 = 0; mi2 < 4; ++mi2) {
            #pragma unroll
            for (int v = 0; v < 4; ++v) {
                int m = m0 + wm + mi2 * 16 + quad * 4 + v;
                out[(size_t)m * 1536 + n] = acc[mi2][ni][v] + bp;
            }
        }
    }
}

// ---------------- FUSED: GRU recurrence + overlapped projection GEMM ----------------
// Grid = 256 blocks x 512 threads (<= 256 CUs => ALL blocks resident by capacity:
// no dispatch-order assumption, no deadlock). Blocks 0..31: the r3 GRU (unchanged
// logic, tagged-data sync through hall64). Blocks 32..255: 224 persistent GEMM
// workers computing logits = Hall @ Wp^T + bias, 128x256 tiles, step-major order,
// each tile gated on its steps' tags in hall64 — so the projection GEMM runs
// CONCURRENTLY with the recurrence, consuming rows as they become final.
// A-operand is read from hall64 payloads with per-word tag verification (correct
// under arbitrary store completion order); K-chain accumulation order is identical
// to the previous k_gemm => bit-identical output values.
__global__ __launch_bounds__(512) void k_fused(
    const unsigned short* __restrict__ whh_bf, const float* __restrict__ gx,
    const float* __restrict__ bhh, const float* __restrict__ h0,
    unsigned long long* __restrict__ hall64,
    const unsigned short* __restrict__ wp_bf, const float* __restrict__ bias,
    float* __restrict__ out)
{
    __shared__ __align__(16) char smem[40448];   // GRU: hs(33792)+gh(6656); GEMM: As(8192)+Bs(16384)
    int blk = blockIdx.x, tid = threadIdx.x;
    int lane = tid & 63, w = tid >> 6;

    if (blk < 32) {
        // ================= GRU: block owns h-dims [blk*16, blk*16+16) =================
        unsigned short* hs = (unsigned short*)smem;          // 32 rows x 528 stride
        float (*gh)[52] = (float(*)[52])(smem + 33792);
        int mi = w & 1, gi = w >> 1;
        int row = lane & 15, quad = lane >> 4;
        int eb = tid >> 4, jl = tid & 15;       // elementwise: batch, local j
        int j = blk * 16 + jl;

        float bhhr = bhh[j], bhhz = bhh[H_ + j], bhhn = bhh[2*H_ + j];
        float hcur = h0[eb * H_ + j];           // fp32 h state lives in a register

        // prologue: W_hh fragments -> registers (waves 0..5), resident for all 63 steps
        short8 barr[16];
        if (w < 6) {
            int gr = gi * H_ + blk * 16 + row;
            const unsigned short* wrow = whh_bf + (size_t)gr * H_;
            #pragma unroll
            for (int kk = 0; kk < 16; ++kk)
                barr[kk] = ld8(wrow + kk * 32 + quad * 8);
        }

        for (int t = 0; t < TS; ++t) {
            // prefetch x-gates (h-independent): latency overlaps the tag-poll
            const float* gxp = gx + (size_t)(t * B_ + eb) * 1536 + j;
            float xr = gxp[0], xz = gxp[512], xn = gxp[1024];

            // ---- tagged staging of hall64[t]: 8192 u64 words, 16 per thread ----
            const unsigned long long* src = hall64 + (size_t)t * (B_ * 256);
            unsigned long long wv[16];
            unsigned want = (unsigned)t;
            for (;;) {
                #pragma unroll
                for (int i = 0; i < 16; ++i)
                    wv[i] = __hip_atomic_load(src + i * 512 + tid,
                                              __ATOMIC_RELAXED, __HIP_MEMORY_SCOPE_AGENT);
                bool ok = true;
                #pragma unroll
                for (int i = 0; i < 16; ++i) ok &= ((unsigned)(wv[i] >> 32) == want);
                if (ok) break;
            }
            #pragma unroll
            for (int i = 0; i < 16; ++i) {
                int idx = i * 512 + tid;                 // word idx: row=idx>>8, dword col=idx&255
                ((unsigned*)(hs + (size_t)(idx >> 8) * 528))[idx & 255] = (unsigned)wv[i];
            }
            __syncthreads();

            if (w < 6) {
                floatx4 ah = {0.f, 0.f, 0.f, 0.f};
                int b_ = mi * 16 + row;                      // A-operand m = batch
                #pragma unroll
                for (int kk = 0; kk < 16; ++kk)
                    ah = __builtin_amdgcn_mfma_f32_16x16x32_bf16(
                            ld8(hs + b_ * 528 + kk * 32 + quad * 8), barr[kk], ah, 0, 0, 0);
                // C/D layout: col(n)=lane&15, row(m)=quad*4+v
                int cb = mi * 16 + quad * 4;
                int cn = gi * 16 + row;
                #pragma unroll
                for (int v = 0; v < 4; ++v) gh[cb + v][cn] = ah[v];
            }
            __syncthreads();
            {
                float hr = gh[eb][jl], hz = gh[eb][16 + jl], hn = gh[eb][32 + jl];
                float r = 1.f / (1.f + __expf(-(xr + hr + bhhr)));
                float z = 1.f / (1.f + __expf(-(xz + hz + bhhz)));
                float nn = tanhf(xn + r * (hn + bhhn));
                hcur = (1.f - z) * nn + z * hcur;
                // pack pair (j even, j odd); fire-and-forget tagged word [t+1 | 2xbf16]
                float hnb = __shfl_xor(hcur, 1);
                if (!(tid & 1)) {
                    unsigned pk = (unsigned)f2bf(hcur) | ((unsigned)f2bf(hnb) << 16);
                    unsigned long long tw = ((unsigned long long)(unsigned)(t + 1) << 32) | pk;
                    __hip_atomic_store(hall64 + ((size_t)(t + 1) * B_ + eb) * 256 + (j >> 1),
                                       tw, __ATOMIC_RELAXED, __HIP_MEMORY_SCOPE_AGENT);
                }
            }
            // no end-of-step barrier needed: hs writes of step t+1 only occur after
            // the post-MFMA barrier; gh reads complete before the next stage barrier.
        }
    } else {
        // ================= persistent GEMM workers =================
        unsigned short* As = (unsigned short*)smem;            // 128 x 32 shorts
        unsigned short* Bs = (unsigned short*)(smem + 8192);   // 256 x 32 shorts
        int g = blk - 32;                                      // 0..223
        int wm = (w & 1) * 64, wn = (w >> 1) * 64;             // 2x4 wave grid, 128x256 tile
        int row16 = lane & 15, quad = lane >> 4;
        int srow = lane >> 2, skc = lane & 3;

        for (int T = g; T < 2000; T += 224) {                  // step-major tile order
            int mx = T / 125, ny = T - mx * 125;
            int m0 = mx * 128, n0 = ny * 256;
            // coarse gate: sleep-poll one tag word of the tile's LAST step.
            // (Per-word verification below makes this purely a politeness filter.)
            if (tid == 0) {
                const unsigned long long* gate = hall64 + (size_t)(4 * mx + 3) * 32 * 256;
                while ((unsigned)(__hip_atomic_load(gate, __ATOMIC_RELAXED,
                                                    __HIP_MEMORY_SCOPE_AGENT) >> 32)
                       != (unsigned)(4 * mx + 3))
                    __builtin_amdgcn_s_sleep(32);
            }

            floatx4 acc[4][4];
            #pragma unroll
            for (int a = 0; a < 4; ++a)
                #pragma unroll
                for (int b = 0; b < 4; ++b) acc[a][b] = (floatx4){0.f, 0.f, 0.f, 0.f};

            for (int k0 = 0; k0 < H_; k0 += 32) {
                __syncthreads();   // also covers gate->stage and tile->tile reuse of As/Bs
                // ---- B stage: Wp rows n0..n0+255, 16B global_load_lds ----
                #pragma unroll
                for (int p = 0; p < 2; ++p) {
                    int seg = w * 2 + p;                       // 0..15, 16 rows each
                    int r = seg * 16 + srow;
                    __builtin_amdgcn_global_load_lds(
                        (const __attribute__((address_space(1))) void*)(wp_bf + (size_t)(n0 + r) * H_ + k0 + skc * 8),
                        (__attribute__((address_space(3))) void*)(Bs + seg * 512),
                        16, 0, 0);
                }
                // ---- A stage from hall64: 2048 u64 words, tag-verified ----
                unsigned long long av[4];
                #pragma unroll
                for (int i = 0; i < 4; ++i) {
                    int idx = i * 512 + tid;
                    av[i] = __hip_atomic_load(
                        hall64 + (size_t)(m0 + (idx >> 4)) * 256 + (k0 >> 1) + (idx & 15),
                        __ATOMIC_RELAXED, __HIP_MEMORY_SCOPE_AGENT);
                }
                #pragma unroll
                for (int i = 0; i < 4; ++i) {
                    int idx = i * 512 + tid;
                    int R = m0 + (idx >> 4);
                    unsigned want = (unsigned)(R >> 5);        // row R carries tag R>>5
                    while ((unsigned)(av[i] >> 32) != want)
                        av[i] = __hip_atomic_load(
                            hall64 + (size_t)R * 256 + (k0 >> 1) + (idx & 15),
                            __ATOMIC_RELAXED, __HIP_MEMORY_SCOPE_AGENT);
                    ((unsigned*)As)[idx] = (unsigned)av[i];    // As[row][col pair] payload
                }
                __syncthreads();
                short8 af[4], bfr[4];
                #pragma unroll
                for (int mi2 = 0; mi2 < 4; ++mi2)
                    af[mi2] = ld8(As + (wm + mi2 * 16 + row16) * 32 + quad * 8);
                #pragma unroll
                for (int ni = 0; ni < 4; ++ni)
                    bfr[ni] = ld8(Bs + (wn + ni * 16 + row16) * 32 + quad * 8);
                #pragma unroll
                for (int mi2 = 0; mi2 < 4; ++mi2)
                    #pragma unroll
                    for (int ni = 0; ni < 4; ++ni)
                        acc[mi2][ni] = __builtin_amdgcn_mfma_f32_16x16x32_bf16(
                                           af[mi2], bfr[ni], acc[mi2][ni], 0, 0, 0);
            }
            // epilogue: remap Hall row m = step*32+b -> out row b*64+step; add bias
            #pragma unroll
            for (int ni = 0; ni < 4; ++ni) {
                int n = n0 + wn + ni * 16 + row16;
                float bp = bias[n];
                #pragma unroll
                for (int mi2 = 0; mi2 < 4; ++mi2) {
                    #pragma unroll
                    for (int v = 0; v < 4; ++v) {
                        int m = m0 + wm + mi2 * 16 + quad * 4 + v;
                        int orow = (m & 31) * 64 + (m >> 5);
                        out[(size_t)orow * V_ + n] = acc[mi2][ni][v] + bp;
                    }
                }
            }
        }
    }
}

// ---------------- in-place log_softmax, one block per output row ----------------
__global__ __launch_bounds__(320) void k_lsm(float* __restrict__ out)
{
    __shared__ float red[5];
    int rown = blockIdx.x;
    int t = rown & 63;
    float4* p = (float4*)(out + (size_t)rown * V_);
    int tid = threadIdx.x;
    if (t == 0) {   // out[:,0,:] = 0 (must rewrite every launch: d_out is re-poisoned)
        float4 z; z.x = z.y = z.z = z.w = 0.f;
        for (int i = tid; i < V_ / 4; i += 320) p[i] = z;
        return;
    }
    float4 v[25];
    #pragma unroll
    for (int jj = 0; jj < 25; ++jj) v[jj] = p[tid + jj * 320];
    float m = -3.4e38f;
    #pragma unroll
    for (int jj = 0; jj < 25; ++jj)
        m = fmaxf(m, fmaxf(fmaxf(v[jj].x, v[jj].y), fmaxf(v[jj].z, v[jj].w)));
    #pragma unroll
    for (int o = 32; o > 0; o >>= 1) m = fmaxf(m, __shfl_xor(m, o));
    if ((tid & 63) == 0) red[tid >> 6] = m;
    __syncthreads();
    m = fmaxf(fmaxf(fmaxf(red[0], red[1]), fmaxf(red[2], red[3])), red[4]);
    __syncthreads();
    float s = 0.f;
    #pragma unroll
    for (int jj = 0; jj < 25; ++jj)
        s += __expf(v[jj].x - m) + __expf(v[jj].y - m) + __expf(v[jj].z - m) + __expf(v[jj].w - m);
    #pragma unroll
    for (int o = 32; o > 0; o >>= 1) s += __shfl_xor(s, o);
    if ((tid & 63) == 0) red[tid >> 6] = s;
    __syncthreads();
    s = red[0] + red[1] + red[2] + red[3] + red[4];
    float lz = m + logf(s);
    #pragma unroll
    for (int jj = 0; jj < 25; ++jj) {
        float4 o4;
        o4.x = v[jj].x - lz; o4.y = v[jj].y - lz; o4.z = v[jj].z - lz; o4.w = v[jj].w - lz;
        p[tid + jj * 320] = o4;
    }
}

extern "C" void kernel_launch(void* const* d_in, const int* in_sizes, int n_in,
                              void* d_out, int out_size, void* d_ws, size_t ws_size,
                              hipStream_t stream) {
    const int*   trg   = (const int*)d_in[0];
    const float* h0    = (const float*)d_in[1];
    const float* embt  = (const float*)d_in[2];
    const float* wih   = (const float*)d_in[3];
    const float* whh   = (const float*)d_in[4];
    const float* bih   = (const float*)d_in[5];
    const float* bhh   = (const float*)d_in[6];
    const float* wproj = (const float*)d_in[7];
    const float* bproj = (const float*)d_in[8];
    float* out = (float*)d_out;

    char* ws = (char*)d_ws;
    size_t off = 0;
    unsigned short* wp_bf  = (unsigned short*)(ws + off); off += (size_t)V_ * H_ * 2;        // 32.77 MB
    unsigned short* wih_bf = (unsigned short*)(ws + off); off += (size_t)3 * H_ * E_ * 2;    // 0.79 MB
    unsigned short* whh_bf = (unsigned short*)(ws + off); off += (size_t)3 * H_ * H_ * 2;    // 1.57 MB
    unsigned short* emb_bf = (unsigned short*)(ws + off); off += (size_t)64 * B_ * E_ * 2;   // 1.05 MB (32 pad rows)
    float*              gx = (float*)(ws + off);          off += (size_t)2048 * 1536 * 4;    // 12.58 MB
    unsigned long long* hall64 = (unsigned long long*)(ws + off); off += (size_t)64 * B_ * 256 * 8; // 4.19 MB
    // total 52.95 MB. gx/hall64 can no longer alias d_out: the fused kernel
    // writes `out` while both are still live.

    k_cvt_wp<<<8000, 256, 0, stream>>>(wproj, wp_bf);                       // V*H/8 threads exact
    k_setup<<<2684, 256, 0, stream>>>(wih, whh, embt, trg, h0,
                                      wih_bf, whh_bf, emb_bf, hall64);
    dim3 xg(16, 12);
    k_xg<<<xg, 256, 0, stream>>>(emb_bf, wih_bf, bih, gx);
    k_fused<<<256, 512, 0, stream>>>(whh_bf, gx, bhh, h0, hall64, wp_bf, bproj, out);
    k_lsm<<<2048, 320, 0, stream>>>(out);
}